// Round 1
// baseline (4495.453 us; speedup 1.0000x reference)
//
#include <hip/hip_runtime.h>
#include <math.h>

namespace {

constexpr int NROW = 16384;   // B*A
constexpr int NF   = 512;     // n_in
constexpr int MIND = 2048;    // inducing points

// ---------------------------------------------------------------- stats ----
__global__ __launch_bounds__(256) void stats_kernel(
    const float* __restrict__ x, const int* __restrict__ mask,
    float* __restrict__ sum, float* __restrict__ sumsq, float* __restrict__ cnt)
{
  const int t = threadIdx.x;
  const int row0 = blockIdx.x * 64;
  float s0 = 0.f, s1 = 0.f, q0 = 0.f, q1 = 0.f, c = 0.f;
  for (int r = 0; r < 64; ++r) {
    const int row = row0 + r;
    const float m = (mask[row] != 0) ? 1.f : 0.f;
    const float v0 = x[(size_t)row * NF + t];
    const float v1 = x[(size_t)row * NF + t + 256];
    s0 += m * v0; q0 += m * v0 * v0;
    s1 += m * v1; q1 += m * v1 * v1;
    c += m;
  }
  atomicAdd(&sum[t], s0);        atomicAdd(&sum[t + 256], s1);
  atomicAdd(&sumsq[t], q0);      atomicAdd(&sumsq[t + 256], q1);
  if (t == 0) atomicAdd(cnt, c);
}

__global__ __launch_bounds__(256) void finalize_stats(
    const float* __restrict__ sum, const float* __restrict__ sumsq,
    const float* __restrict__ cnt, const float* __restrict__ gamma,
    float* __restrict__ meanv, float* __restrict__ stdv,
    float* __restrict__ zsv, float* __restrict__ giv)
{
  const int f = blockIdx.x * 256 + threadIdx.x;   // <<<2,256>>>
  const float n = cnt[0];
  const float mu = sum[f] / n;
  const float var = (sumsq[f] - sum[f] * mu) / (n - 1.0f);
  const float sd = sqrtf(var) + 1e-5f;
  const float g = gamma[f];
  const float g2 = g * g + 0.001f;
  meanv[f] = mu;
  stdv[f]  = sd;
  zsv[f]   = 1.0f / (sd * g2);
  giv[f]   = 1.0f / g2;
}

// z rows (masked, normalized, /g2) + zi rows (/g2) + squared row norms
__global__ __launch_bounds__(256) void make_z(
    const float* __restrict__ x, const int* __restrict__ mask,
    const float* __restrict__ ip, const float* __restrict__ meanv,
    const float* __restrict__ zsv, const float* __restrict__ giv,
    float* __restrict__ Z, float* __restrict__ Zi,
    float* __restrict__ rnorm, float* __restrict__ cnorm)
{
  const int row = blockIdx.x;
  const int t = threadIdx.x;
  float v0, v1;
  if (row < NROW) {
    const float m = (mask[row] != 0) ? 1.f : 0.f;
    v0 = (x[(size_t)row * NF + t      ] - meanv[t      ]) * zsv[t      ] * m;
    v1 = (x[(size_t)row * NF + t + 256] - meanv[t + 256]) * zsv[t + 256] * m;
    Z[(size_t)row * NF + t] = v0;
    Z[(size_t)row * NF + t + 256] = v1;
  } else {
    const int r = row - NROW;
    v0 = ip[(size_t)r * NF + t      ] * giv[t      ];
    v1 = ip[(size_t)r * NF + t + 256] * giv[t + 256];
    Zi[(size_t)r * NF + t] = v0;
    Zi[(size_t)r * NF + t + 256] = v1;
  }
  float nrm = v0 * v0 + v1 * v1;
  #pragma unroll
  for (int off = 32; off; off >>= 1) nrm += __shfl_xor(nrm, off);
  __shared__ float red[4];
  if ((t & 63) == 0) red[t >> 6] = nrm;
  __syncthreads();
  if (t == 0) {
    const float s = red[0] + red[1] + red[2] + red[3];
    if (row < NROW) rnorm[row] = s; else cnorm[row - NROW] = s;
  }
}

// ---------------------------------------------------------------- GEMM ----
// C[M,N] = A[M,K] * B   (BNT: B stored [N,K]; else [K,N])
// EPI 0: store C
// EPI 1: C = exp(-|rn[i]+cn[j]-2S|) (+regdiag on i==j)
// EPI 2: no store; atomicAdd varacc[i] += sum_j S_ij * KxT[i,j]
// EPI 3: C = (S*stdv[j]+meanv[j]) * (mask[i]!=0)
template <int BM, int BN, int BK, int TM, int TN, bool BNT, int EPI>
__global__ __launch_bounds__(256) void gemm_k(
    const float* __restrict__ A, const float* __restrict__ B,
    float* __restrict__ C, int M, int N, int K, int ldc,
    const float* __restrict__ rn, const float* __restrict__ cn, float regdiag,
    const float* __restrict__ KxT, float* __restrict__ varacc,
    const float* __restrict__ stdv, const float* __restrict__ meanv,
    const int* __restrict__ mask)
{
  static_assert(BK == 16, "loaders assume BK==16");
  static_assert((BM / TM) * (BN / TN) == 256, "256 threads");
  static_assert(TM % 4 == 0 && TN % 4 == 0, "float4 micro");
  static_assert(EPI != 2 || (BN / TN) == 16, "EPI2 shuffle assumes TX==16");
  constexpr int TX = BN / TN;
  constexpr int NLA = (BM * BK) / 1024;
  constexpr int NLB = (BN * BK) / 1024;

  const int tid = threadIdx.x;
  const int tx = tid % TX, ty = tid / TX;
  const int bn = blockIdx.x, bm = blockIdx.y;

  __shared__ float As[BK][BM + 4];
  __shared__ float Bs[BK][BN + 4];

  float acc[TM][TN] = {};

  const float* Ag = A + (size_t)bm * BM * K;
  const float* Bg = BNT ? (B + (size_t)bn * BN * K) : (B + bn * BN);

  for (int k0 = 0; k0 < K; k0 += BK) {
    #pragma unroll
    for (int l = 0; l < NLA; ++l) {
      const int v = tid + l * 256;
      const int r = v >> 2, c4 = (v & 3) << 2;
      const float4 av = *(const float4*)(Ag + (size_t)r * K + k0 + c4);
      As[c4 + 0][r] = av.x; As[c4 + 1][r] = av.y;
      As[c4 + 2][r] = av.z; As[c4 + 3][r] = av.w;
    }
    if constexpr (BNT) {
      #pragma unroll
      for (int l = 0; l < NLB; ++l) {
        const int v = tid + l * 256;
        const int r = v >> 2, c4 = (v & 3) << 2;
        const float4 bv = *(const float4*)(Bg + (size_t)r * K + k0 + c4);
        Bs[c4 + 0][r] = bv.x; Bs[c4 + 1][r] = bv.y;
        Bs[c4 + 2][r] = bv.z; Bs[c4 + 3][r] = bv.w;
      }
    } else {
      #pragma unroll
      for (int l = 0; l < NLB; ++l) {
        const int v = tid + l * 256;
        const int kr = v / (BN / 4), nc = (v % (BN / 4)) << 2;
        *(float4*)&Bs[kr][nc] = *(const float4*)(Bg + (size_t)(k0 + kr) * N + nc);
      }
    }
    __syncthreads();
    #pragma unroll
    for (int kk = 0; kk < BK; ++kk) {
      float a[TM], b[TN];
      #pragma unroll
      for (int ch = 0; ch < TM / 4; ++ch) {
        const float4 t4 = *(const float4*)&As[kk][ch * (BM / 2) + ty * 4];
        a[ch * 4 + 0] = t4.x; a[ch * 4 + 1] = t4.y;
        a[ch * 4 + 2] = t4.z; a[ch * 4 + 3] = t4.w;
      }
      #pragma unroll
      for (int ch = 0; ch < TN / 4; ++ch) {
        const float4 t4 = *(const float4*)&Bs[kk][ch * (BN / 2) + tx * 4];
        b[ch * 4 + 0] = t4.x; b[ch * 4 + 1] = t4.y;
        b[ch * 4 + 2] = t4.z; b[ch * 4 + 3] = t4.w;
      }
      #pragma unroll
      for (int i = 0; i < TM; ++i)
        #pragma unroll
        for (int j = 0; j < TN; ++j)
          acc[i][j] += a[i] * b[j];
    }
    __syncthreads();
  }

  const int grb = bm * BM, gcb = bn * BN;
  if constexpr (EPI == 2) {
    #pragma unroll
    for (int ci = 0; ci < TM / 4; ++ci)
      #pragma unroll
      for (int ii = 0; ii < 4; ++ii) {
        const int gr = grb + ci * (BM / 2) + ty * 4 + ii;
        float r = 0.f;
        #pragma unroll
        for (int cj = 0; cj < TN / 4; ++cj) {
          const int gc = gcb + cj * (BN / 2) + tx * 4;
          const float4 kx4 = *(const float4*)(KxT + (size_t)gr * N + gc);
          const float* av = acc[ci * 4 + ii] + cj * 4;
          r += av[0] * kx4.x + av[1] * kx4.y + av[2] * kx4.z + av[3] * kx4.w;
        }
        r += __shfl_xor(r, 1); r += __shfl_xor(r, 2);
        r += __shfl_xor(r, 4); r += __shfl_xor(r, 8);
        if (tx == 0) atomicAdd(&varacc[gr], r);
      }
  } else {
    #pragma unroll
    for (int ci = 0; ci < TM / 4; ++ci)
      #pragma unroll
      for (int ii = 0; ii < 4; ++ii) {
        const int gr = grb + ci * (BM / 2) + ty * 4 + ii;
        float rni = 0.f, mrow = 0.f;
        if constexpr (EPI == 1) rni = rn[gr];
        if constexpr (EPI == 3) mrow = (mask[gr] != 0) ? 1.f : 0.f;
        #pragma unroll
        for (int cj = 0; cj < TN / 4; ++cj) {
          const int gc = gcb + cj * (BN / 2) + tx * 4;
          const float* av = acc[ci * 4 + ii] + cj * 4;
          float ov[4];
          #pragma unroll
          for (int e = 0; e < 4; ++e) {
            if constexpr (EPI == 0) {
              ov[e] = av[e];
            } else if constexpr (EPI == 1) {
              const float d = rni + cn[gc + e] - 2.f * av[e];
              float v = expf(-fabsf(d));
              if (gr == gc + e) v += regdiag;
              ov[e] = v;
            } else {
              ov[e] = (av[e] * stdv[gc + e] + meanv[gc + e]) * mrow;
            }
          }
          float4 o4; o4.x = ov[0]; o4.y = ov[1]; o4.z = ov[2]; o4.w = ov[3];
          *(float4*)(C + (size_t)gr * ldc + gc) = o4;
        }
      }
  }
}

// ------------------------------------------------- blocked Gauss-Jordan ----
// In-place inverse of SPD A[2048x2048], NB=64.
__global__ __launch_bounds__(256) void gj_diag(
    float* __restrict__ A, float* __restrict__ P, int o)
{
  __shared__ float D[64][68];
  const int t = threadIdx.x;
  #pragma unroll
  for (int l = 0; l < 4; ++l) {
    const int v = t + l * 256;
    const int r = v >> 4, c4 = (v & 15) << 2;
    *(float4*)&D[r][c4] = *(const float4*)(A + (size_t)(o + r) * MIND + o + c4);
  }
  __syncthreads();
  const int i = t >> 2, c0 = (t & 3) * 16;
  for (int s = 0; s < 64; ++s) {
    const float p = 1.0f / D[s][s];
    if (t < 64 && t != s) D[s][t] *= p;
    __syncthreads();
    if (i != s) {
      const float f = D[i][s];   // all 4 threads of row i are in one wave: read precedes write
      #pragma unroll
      for (int c = c0; c < c0 + 16; c += 4) {
        float4 ds = *(const float4*)&D[s][c];
        float4 di = *(const float4*)&D[i][c];
        di.x -= f * ds.x; di.y -= f * ds.y; di.z -= f * ds.z; di.w -= f * ds.w;
        *(float4*)&D[i][c] = di;
      }
      if (s >= c0 && s < c0 + 16) D[i][s] = -f * p;   // fixes the garbage lane
    }
    if (t == 0) D[s][s] = p;
    __syncthreads();
  }
  #pragma unroll
  for (int l = 0; l < 4; ++l) {
    const int v = t + l * 256;
    const int r = v >> 4, c4 = (v & 15) << 2;
    const float4 dv = *(const float4*)&D[r][c4];
    *(float4*)(P + r * 64 + c4) = dv;
    *(float4*)(A + (size_t)(o + r) * MIND + o + c4) = dv;
  }
}

__global__ __launch_bounds__(256) void gj_row(
    float* __restrict__ A, const float* __restrict__ P, int o)
{
  const int j0 = blockIdx.x * 64;
  if (j0 == o) return;
  __shared__ float Pt[64][68];   // Pt[s][r] = P[r][s]
  __shared__ float Bt[64][68];   // Bt[s][c] = A[o+s][j0+c]
  const int t = threadIdx.x;
  #pragma unroll
  for (int l = 0; l < 4; ++l) {
    const int v = t + l * 256;
    const int r = v >> 4, c4 = (v & 15) << 2;
    const float4 pv = *(const float4*)(P + r * 64 + c4);
    Pt[c4 + 0][r] = pv.x; Pt[c4 + 1][r] = pv.y;
    Pt[c4 + 2][r] = pv.z; Pt[c4 + 3][r] = pv.w;
    *(float4*)&Bt[r][c4] = *(const float4*)(A + (size_t)(o + r) * MIND + j0 + c4);
  }
  __syncthreads();
  const int ty = t >> 4, tx = t & 15;
  float acc[4][4] = {};
  for (int s = 0; s < 64; ++s) {
    const float4 a4 = *(const float4*)&Pt[s][ty * 4];
    const float4 b4 = *(const float4*)&Bt[s][tx * 4];
    const float a[4] = {a4.x, a4.y, a4.z, a4.w};
    const float b[4] = {b4.x, b4.y, b4.z, b4.w};
    #pragma unroll
    for (int i = 0; i < 4; ++i)
      #pragma unroll
      for (int j = 0; j < 4; ++j) acc[i][j] += a[i] * b[j];
  }
  #pragma unroll
  for (int i = 0; i < 4; ++i) {
    float4 o4; o4.x = acc[i][0]; o4.y = acc[i][1]; o4.z = acc[i][2]; o4.w = acc[i][3];
    *(float4*)(A + (size_t)(o + ty * 4 + i) * MIND + j0 + tx * 4) = o4;
  }
}

__global__ __launch_bounds__(256) void gj_big(float* __restrict__ A, int o)
{
  const int j0 = blockIdx.x * 64, i0 = blockIdx.y * 64;
  if (i0 == o || j0 == o) return;
  __shared__ float Ct[64][68];   // Ct[k][r] = A[i0+r][o+k]  (old col panel)
  __shared__ float Rw[64][68];   // Rw[k][c] = A[o+k][j0+c]  (new row panel)
  const int t = threadIdx.x;
  #pragma unroll
  for (int l = 0; l < 4; ++l) {
    const int v = t + l * 256;
    const int r = v >> 4, c4 = (v & 15) << 2;
    const float4 av = *(const float4*)(A + (size_t)(i0 + r) * MIND + o + c4);
    Ct[c4 + 0][r] = av.x; Ct[c4 + 1][r] = av.y;
    Ct[c4 + 2][r] = av.z; Ct[c4 + 3][r] = av.w;
    *(float4*)&Rw[r][c4] = *(const float4*)(A + (size_t)(o + r) * MIND + j0 + c4);
  }
  __syncthreads();
  const int ty = t >> 4, tx = t & 15;
  float acc[4][4] = {};
  for (int k = 0; k < 64; ++k) {
    const float4 a4 = *(const float4*)&Ct[k][ty * 4];
    const float4 b4 = *(const float4*)&Rw[k][tx * 4];
    const float a[4] = {a4.x, a4.y, a4.z, a4.w};
    const float b[4] = {b4.x, b4.y, b4.z, b4.w};
    #pragma unroll
    for (int i = 0; i < 4; ++i)
      #pragma unroll
      for (int j = 0; j < 4; ++j) acc[i][j] += a[i] * b[j];
  }
  #pragma unroll
  for (int i = 0; i < 4; ++i) {
    float* cp = A + (size_t)(i0 + ty * 4 + i) * MIND + j0 + tx * 4;
    float4 cv = *(const float4*)cp;
    cv.x -= acc[i][0]; cv.y -= acc[i][1]; cv.z -= acc[i][2]; cv.w -= acc[i][3];
    *(float4*)cp = cv;
  }
}

__global__ __launch_bounds__(256) void gj_col(
    float* __restrict__ A, const float* __restrict__ P, int o)
{
  const int i0 = blockIdx.x * 64;
  if (i0 == o) return;
  __shared__ float Ot[64][68];   // Ot[s][r] = A[i0+r][o+s]  (old col panel)
  __shared__ float Pl[64][68];   // Pl[s][c] = P[s][c]
  const int t = threadIdx.x;
  #pragma unroll
  for (int l = 0; l < 4; ++l) {
    const int v = t + l * 256;
    const int r = v >> 4, c4 = (v & 15) << 2;
    const float4 av = *(const float4*)(A + (size_t)(i0 + r) * MIND + o + c4);
    Ot[c4 + 0][r] = av.x; Ot[c4 + 1][r] = av.y;
    Ot[c4 + 2][r] = av.z; Ot[c4 + 3][r] = av.w;
    *(float4*)&Pl[r][c4] = *(const float4*)(P + r * 64 + c4);
  }
  __syncthreads();
  const int ty = t >> 4, tx = t & 15;
  float acc[4][4] = {};
  for (int s = 0; s < 64; ++s) {
    const float4 a4 = *(const float4*)&Ot[s][ty * 4];
    const float4 b4 = *(const float4*)&Pl[s][tx * 4];
    const float a[4] = {a4.x, a4.y, a4.z, a4.w};
    const float b[4] = {b4.x, b4.y, b4.z, b4.w};
    #pragma unroll
    for (int i = 0; i < 4; ++i)
      #pragma unroll
      for (int j = 0; j < 4; ++j) acc[i][j] += a[i] * b[j];
  }
  #pragma unroll
  for (int i = 0; i < 4; ++i) {
    float4 o4;
    o4.x = -acc[i][0]; o4.y = -acc[i][1]; o4.z = -acc[i][2]; o4.w = -acc[i][3];
    *(float4*)(A + (size_t)(i0 + ty * 4 + i) * MIND + o + tx * 4) = o4;
  }
}

__global__ __launch_bounds__(256) void var_finalize(
    const float* __restrict__ varacc, const int* __restrict__ mask,
    float* __restrict__ outv)
{
  const int i = blockIdx.x * 256 + threadIdx.x;
  const float m = (mask[i] != 0) ? 1.f : 0.f;
  outv[i] = (1.0f - varacc[i]) * m;
}

}  // namespace

extern "C" void kernel_launch(void* const* d_in, const int* in_sizes, int n_in,
                              void* d_out, int out_size, void* d_ws, size_t ws_size,
                              hipStream_t stream)
{
  (void)in_sizes; (void)n_in; (void)out_size; (void)ws_size;
  const float* x     = (const float*)d_in[0];
  const int*   mask  = (const int*)d_in[1];
  const float* ip    = (const float*)d_in[2];
  const float* gamma = (const float*)d_in[3];
  float* out = (float*)d_out;

  float* w      = (float*)d_ws;
  float* sum    = w;                     // 512
  float* sumsq  = w + 512;               // 512
  float* cnt    = w + 1024;              // 1 (padded to 512)
  float* varacc = w + 1536;              // 16384
  float* meanv  = w + 17920;             // 512
  float* stdv   = meanv + 512;           // 512
  float* zsv    = stdv + 512;            // 512
  float* giv    = zsv + 512;             // 512
  float* Z      = giv + 512;             // NROW*NF
  float* Zi     = Z + (size_t)NROW * NF; // MIND*NF
  float* rnorm  = Zi + (size_t)MIND * NF;
  float* cnorm  = rnorm + NROW;
  float* Kx     = cnorm + MIND;               // NROW*MIND (134 MB)
  float* Ai     = Kx + (size_t)NROW * MIND;   // MIND*MIND (Kreg -> Kinv in place)
  float* Pd     = Ai + (size_t)MIND * MIND;   // 64*64 diag-inverse scratch
  float* R      = Pd + 4096;                  // MIND*NF

  // zero accumulators (sum/sumsq/cnt/varacc)
  hipMemsetAsync(w, 0, 17920 * sizeof(float), stream);

  stats_kernel<<<256, 256, 0, stream>>>(x, mask, sum, sumsq, cnt);
  finalize_stats<<<2, 256, 0, stream>>>(sum, sumsq, cnt, gamma, meanv, stdv, zsv, giv);
  make_z<<<NROW + MIND, 256, 0, stream>>>(x, mask, ip, meanv, zsv, giv, Z, Zi, rnorm, cnorm);

  // Kx = exp(-|rn_i + cn_j - 2 Z Zi^T|)
  gemm_k<128, 128, 16, 8, 8, true, 1><<<dim3(MIND / 128, NROW / 128), 256, 0, stream>>>(
      Z, Zi, Kx, NROW, MIND, NF, MIND, rnorm, cnorm, 0.f,
      nullptr, nullptr, nullptr, nullptr, nullptr);
  // Kreg = exp(-|...|) + 0.05 I  (into Ai)
  gemm_k<128, 128, 16, 8, 8, true, 1><<<dim3(MIND / 128, MIND / 128), 256, 0, stream>>>(
      Zi, Zi, Ai, MIND, MIND, NF, MIND, cnorm, cnorm, 0.05f,
      nullptr, nullptr, nullptr, nullptr, nullptr);

  // in-place blocked Gauss-Jordan inverse (SPD, no pivoting)
  for (int o = 0; o < MIND; o += 64) {
    gj_diag<<<1, 256, 0, stream>>>(Ai, Pd, o);
    gj_row<<<32, 256, 0, stream>>>(Ai, Pd, o);
    gj_big<<<dim3(32, 32), 256, 0, stream>>>(Ai, o);
    gj_col<<<32, 256, 0, stream>>>(Ai, Pd, o);
  }

  // R = Kinv * P
  gemm_k<64, 64, 16, 4, 4, false, 0><<<dim3(NF / 64, MIND / 64), 256, 0, stream>>>(
      Ai, ip, R, MIND, NF, MIND, NF, nullptr, nullptr, 0.f,
      nullptr, nullptr, nullptr, nullptr, nullptr);

  // varacc_i = sum_j (Kx Kinv)_ij * Kx_ij   (T never materialized)
  gemm_k<128, 128, 16, 8, 8, false, 2><<<dim3(MIND / 128, NROW / 128), 256, 0, stream>>>(
      Kx, Ai, nullptr, NROW, MIND, MIND, 0, nullptr, nullptr, 0.f,
      Kx, varacc, nullptr, nullptr, nullptr);

  // x_new = (Kx * R) * std + mean, masked
  gemm_k<128, 128, 16, 8, 8, false, 3><<<dim3(NF / 128, NROW / 128), 256, 0, stream>>>(
      Kx, R, out, NROW, NF, MIND, NF, nullptr, nullptr, 0.f,
      nullptr, nullptr, stdv, meanv, mask);

  var_finalize<<<NROW / 256, 256, 0, stream>>>(varacc, mask, out + (size_t)NROW * NF);
}

// Round 2
// 2440.066 us; speedup vs baseline: 1.8423x; 1.8423x over previous
//
#include <hip/hip_runtime.h>
#include <math.h>
#include <stdint.h>

namespace {

constexpr int NROW = 16384;   // B*A
constexpr int NF   = 512;     // n_in
constexpr int MIND = 2048;    // inducing points
constexpr float CC = 0.98f;   // centering constant: Kx ~ exp(-d), d ~ 0.004 +- few e-3

typedef _Float16 half8 __attribute__((ext_vector_type(8)));
typedef float floatx4 __attribute__((ext_vector_type(4)));

__device__ __forceinline__ void gload16(const void* g, void* l) {
  // async global->LDS, 16B/lane; LDS dest semantics: wave-uniform base + lane*16
  __builtin_amdgcn_global_load_lds(
      (__attribute__((address_space(1))) void*)g,
      (__attribute__((address_space(3))) void*)l, 16, 0, 0);
}

// ---------------------------------------------------------------- stats ----
__global__ __launch_bounds__(256) void stats_kernel(
    const float* __restrict__ x, const int* __restrict__ mask,
    float* __restrict__ sum, float* __restrict__ sumsq, float* __restrict__ cnt)
{
  const int t = threadIdx.x;
  const int row0 = blockIdx.x * 64;
  float s0 = 0.f, s1 = 0.f, q0 = 0.f, q1 = 0.f, c = 0.f;
  for (int r = 0; r < 64; ++r) {
    const int row = row0 + r;
    const float m = (mask[row] != 0) ? 1.f : 0.f;
    const float v0 = x[(size_t)row * NF + t];
    const float v1 = x[(size_t)row * NF + t + 256];
    s0 += m * v0; q0 += m * v0 * v0;
    s1 += m * v1; q1 += m * v1 * v1;
    c += m;
  }
  atomicAdd(&sum[t], s0);        atomicAdd(&sum[t + 256], s1);
  atomicAdd(&sumsq[t], q0);      atomicAdd(&sumsq[t + 256], q1);
  if (t == 0) atomicAdd(cnt, c);
}

__global__ __launch_bounds__(256) void finalize_stats(
    const float* __restrict__ sum, const float* __restrict__ sumsq,
    const float* __restrict__ cnt, const float* __restrict__ gamma,
    float* __restrict__ meanv, float* __restrict__ stdv,
    float* __restrict__ zsv, float* __restrict__ giv)
{
  const int f = blockIdx.x * 256 + threadIdx.x;   // <<<2,256>>>
  const float n = cnt[0];
  const float mu = sum[f] / n;
  const float var = (sumsq[f] - sum[f] * mu) / (n - 1.0f);
  const float sd = sqrtf(var) + 1e-5f;
  const float g = gamma[f];
  const float g2 = g * g + 0.001f;
  meanv[f] = mu;
  stdv[f]  = sd;
  zsv[f]   = 1.0f / (sd * g2);
  giv[f]   = 1.0f / g2;
}

// z rows (masked, normalized, /g2) as fp16 + zi rows (/g2) fp16 + fp32 norms
// norms computed from the fp16-ROUNDED values so d_jj ~ 0 exactly.
__global__ __launch_bounds__(256) void make_z(
    const float* __restrict__ x, const int* __restrict__ mask,
    const float* __restrict__ ip, const float* __restrict__ meanv,
    const float* __restrict__ zsv, const float* __restrict__ giv,
    _Float16* __restrict__ Zh, _Float16* __restrict__ Zih,
    float* __restrict__ rnorm, float* __restrict__ cnorm)
{
  const int row = blockIdx.x;
  const int t = threadIdx.x;
  float v0, v1;
  if (row < NROW) {
    const float m = (mask[row] != 0) ? 1.f : 0.f;
    v0 = (x[(size_t)row * NF + t      ] - meanv[t      ]) * zsv[t      ] * m;
    v1 = (x[(size_t)row * NF + t + 256] - meanv[t + 256]) * zsv[t + 256] * m;
    const _Float16 h0 = (_Float16)v0, h1 = (_Float16)v1;
    Zh[(size_t)row * NF + t] = h0;
    Zh[(size_t)row * NF + t + 256] = h1;
    v0 = (float)h0; v1 = (float)h1;
  } else {
    const int r = row - NROW;
    v0 = ip[(size_t)r * NF + t      ] * giv[t      ];
    v1 = ip[(size_t)r * NF + t + 256] * giv[t + 256];
    const _Float16 h0 = (_Float16)v0, h1 = (_Float16)v1;
    Zih[(size_t)r * NF + t] = h0;
    Zih[(size_t)r * NF + t + 256] = h1;
    v0 = (float)h0; v1 = (float)h1;
  }
  float nrm = v0 * v0 + v1 * v1;
  #pragma unroll
  for (int off = 32; off; off >>= 1) nrm += __shfl_xor(nrm, off);
  __shared__ float red[4];
  if ((t & 63) == 0) red[t >> 6] = nrm;
  __syncthreads();
  if (t == 0) {
    const float s = red[0] + red[1] + red[2] + red[3];
    if (row < NROW) rnorm[row] = s; else cnorm[row - NROW] = s;
  }
}

// ---------------------------------------------------------- MFMA GEMM ------
// S[M,N] = A[M,K] * B[N,K]^T, both fp16 K-contiguous, fp32 accumulate.
// 128x128 tile, BK=32, 4 waves each computing 64x64 via 4x4 of 16x16x32 MFMA.
// EPI 0: DKout = fp16(exp(-|rn_i + cn_j - 2S|) - CC)                [Kx gen]
// EPI 1: Cf = exp(-|rn_i + cn_j - 2S|) + 0.05*(i==j)  fp32          [Kreg]
// EPI 2: varacc_i += sum_j (S_ij + CC*u_j) * (CC + DK_ij)           [t o Kx]
// EPI 3: Cf = ((S_ij + CC*colsumR_j)*stdv_j + meanv_j) * mask_i     [x_new]
template <int EPI>
__global__ __launch_bounds__(256) void mfma_gemm(
    const _Float16* __restrict__ A, const _Float16* __restrict__ B,
    int M, int N, int K,
    const float* __restrict__ rn, const float* __restrict__ cn,
    _Float16* __restrict__ DKout, float* __restrict__ Cf,
    const _Float16* __restrict__ DK, const float* __restrict__ u,
    float* __restrict__ varacc,
    const float* __restrict__ colsumR,
    const float* __restrict__ stdv, const float* __restrict__ meanv,
    const int* __restrict__ mask)
{
  __shared__ __align__(16) _Float16 As[128 * 32];
  __shared__ __align__(16) _Float16 Bs[128 * 32];
  const int tid = threadIdx.x;
  const int w = tid >> 6, L = tid & 63;
  const int wm = w >> 1, wn = w & 1;
  const int bn = blockIdx.x, bm = blockIdx.y;
  const int lq = L >> 4;        // quad (0..3)
  const int lr = L & 15;        // lane-in-quad

  floatx4 acc[4][4] = {};

  const _Float16* Ag = A + (size_t)(bm * 128) * K;
  const _Float16* Bg = B + (size_t)(bn * 128) * K;
  const int srow = w * 32 + (L >> 2);   // staging row (+ t*16)
  const int scol = (L & 3) * 8;         // staging col (fp16 elems)

  for (int k0 = 0; k0 < K; k0 += 32) {
    #pragma unroll
    for (int t = 0; t < 2; ++t) {
      const int r = srow + t * 16;
      gload16(Ag + (size_t)r * K + k0 + scol, As + r * 32 + scol);
      gload16(Bg + (size_t)r * K + k0 + scol, Bs + r * 32 + scol);
    }
    __syncthreads();
    half8 af[4], bf[4];
    #pragma unroll
    for (int mi = 0; mi < 4; ++mi)
      af[mi] = *(const half8*)&As[(wm * 64 + mi * 16 + lr) * 32 + lq * 8];
    #pragma unroll
    for (int ni = 0; ni < 4; ++ni)
      bf[ni] = *(const half8*)&Bs[(wn * 64 + ni * 16 + lr) * 32 + lq * 8];
    #pragma unroll
    for (int mi = 0; mi < 4; ++mi)
      #pragma unroll
      for (int ni = 0; ni < 4; ++ni)
        acc[mi][ni] = __builtin_amdgcn_mfma_f32_16x16x32_f16(
            af[mi], bf[ni], acc[mi][ni], 0, 0, 0);
    __syncthreads();
  }

  // C/D layout: col = lane&15, row = (lane>>4)*4 + reg   [m89/m91 verified]
  const int grb = bm * 128 + wm * 64;
  const int gcb = bn * 128 + wn * 64;

  if constexpr (EPI == 2) {
    #pragma unroll
    for (int mi = 0; mi < 4; ++mi)
      #pragma unroll
      for (int e = 0; e < 4; ++e) {
        const int gr = grb + mi * 16 + lq * 4 + e;
        float partial = 0.f;
        #pragma unroll
        for (int ni = 0; ni < 4; ++ni) {
          const int gc = gcb + ni * 16 + lr;
          const float t = acc[mi][ni][e] + CC * u[gc];
          const float kx = CC + (float)DK[(size_t)gr * N + gc];
          partial += t * kx;
        }
        partial += __shfl_xor(partial, 1);
        partial += __shfl_xor(partial, 2);
        partial += __shfl_xor(partial, 4);
        partial += __shfl_xor(partial, 8);
        if (lr == 0) atomicAdd(&varacc[gr], partial);
      }
  } else if constexpr (EPI == 3) {
    #pragma unroll
    for (int mi = 0; mi < 4; ++mi)
      #pragma unroll
      for (int e = 0; e < 4; ++e) {
        const int gr = grb + mi * 16 + lq * 4 + e;
        const float mrow = (mask[gr] != 0) ? 1.f : 0.f;
        #pragma unroll
        for (int ni = 0; ni < 4; ++ni) {
          const int gc = gcb + ni * 16 + lr;
          const float v = acc[mi][ni][e] + CC * colsumR[gc];
          Cf[(size_t)gr * N + gc] = (v * stdv[gc] + meanv[gc]) * mrow;
        }
      }
  } else {
    #pragma unroll
    for (int mi = 0; mi < 4; ++mi)
      #pragma unroll
      for (int e = 0; e < 4; ++e) {
        const int gr = grb + mi * 16 + lq * 4 + e;
        const float rni = rn[gr];
        #pragma unroll
        for (int ni = 0; ni < 4; ++ni) {
          const int gc = gcb + ni * 16 + lr;
          const float d = rni + cn[gc] - 2.f * acc[mi][ni][e];
          float kx = expf(-fabsf(d));
          if constexpr (EPI == 0) {
            DKout[(size_t)gr * N + gc] = (_Float16)(kx - CC);
          } else {
            if (gr == gc) kx += 0.05f;
            Cf[(size_t)gr * N + gc] = kx;
          }
        }
      }
  }
}

// ------------------------------------------------------------ fp32 GEMM ----
// C[M,N] = A[M,K]*B[K,N], 64x64 tile (used only for R = Kinv * P)
__global__ __launch_bounds__(256) void gemm_f32(
    const float* __restrict__ A, const float* __restrict__ B,
    float* __restrict__ C, int M, int N, int K)
{
  constexpr int BM = 64, BN = 64, BK = 16;
  const int tid = threadIdx.x;
  const int tx = tid % 16, ty = tid / 16;
  const int bn = blockIdx.x, bm = blockIdx.y;
  __shared__ float As[BK][BM + 4];
  __shared__ float Bs[BK][BN + 4];
  float acc[4][4] = {};
  const float* Ag = A + (size_t)bm * BM * K;
  const float* Bg = B + bn * BN;
  for (int k0 = 0; k0 < K; k0 += BK) {
    {
      const int r = tid >> 2, c4 = (tid & 3) << 2;
      const float4 av = *(const float4*)(Ag + (size_t)r * K + k0 + c4);
      As[c4 + 0][r] = av.x; As[c4 + 1][r] = av.y;
      As[c4 + 2][r] = av.z; As[c4 + 3][r] = av.w;
      const int kr = tid / 16, nc = (tid % 16) << 2;
      *(float4*)&Bs[kr][nc] = *(const float4*)(Bg + (size_t)(k0 + kr) * N + nc);
    }
    __syncthreads();
    #pragma unroll
    for (int kk = 0; kk < BK; ++kk) {
      const float4 a4 = *(const float4*)&As[kk][ty * 4];
      const float4 b4 = *(const float4*)&Bs[kk][tx * 4];
      const float a[4] = {a4.x, a4.y, a4.z, a4.w};
      const float b[4] = {b4.x, b4.y, b4.z, b4.w};
      #pragma unroll
      for (int i = 0; i < 4; ++i)
        #pragma unroll
        for (int j = 0; j < 4; ++j) acc[i][j] += a[i] * b[j];
    }
    __syncthreads();
  }
  #pragma unroll
  for (int i = 0; i < 4; ++i) {
    float4 o4; o4.x = acc[i][0]; o4.y = acc[i][1]; o4.z = acc[i][2]; o4.w = acc[i][3];
    *(float4*)(C + (size_t)(bm * BM + ty * 4 + i) * N + bn * BN + tx * 4) = o4;
  }
}

// ------------------------------------------------- blocked Gauss-Jordan ----
__global__ __launch_bounds__(256) void gj_diag(
    float* __restrict__ A, float* __restrict__ P, int o)
{
  __shared__ float D[64][68];
  const int t = threadIdx.x;
  #pragma unroll
  for (int l = 0; l < 4; ++l) {
    const int v = t + l * 256;
    const int r = v >> 4, c4 = (v & 15) << 2;
    *(float4*)&D[r][c4] = *(const float4*)(A + (size_t)(o + r) * MIND + o + c4);
  }
  __syncthreads();
  const int i = t >> 2, c0 = (t & 3) * 16;
  for (int s = 0; s < 64; ++s) {
    const float p = 1.0f / D[s][s];
    if (t < 64 && t != s) D[s][t] *= p;
    __syncthreads();
    if (i != s) {
      const float f = D[i][s];
      #pragma unroll
      for (int c = c0; c < c0 + 16; c += 4) {
        float4 ds = *(const float4*)&D[s][c];
        float4 di = *(const float4*)&D[i][c];
        di.x -= f * ds.x; di.y -= f * ds.y; di.z -= f * ds.z; di.w -= f * ds.w;
        *(float4*)&D[i][c] = di;
      }
      if (s >= c0 && s < c0 + 16) D[i][s] = -f * p;
    }
    if (t == 0) D[s][s] = p;
    __syncthreads();
  }
  #pragma unroll
  for (int l = 0; l < 4; ++l) {
    const int v = t + l * 256;
    const int r = v >> 4, c4 = (v & 15) << 2;
    const float4 dv = *(const float4*)&D[r][c4];
    *(float4*)(P + r * 64 + c4) = dv;
    *(float4*)(A + (size_t)(o + r) * MIND + o + c4) = dv;
  }
}

__global__ __launch_bounds__(256) void gj_row(
    float* __restrict__ A, const float* __restrict__ P, int o)
{
  const int j0 = blockIdx.x * 64;
  if (j0 == o) return;
  __shared__ float Pt[64][68];
  __shared__ float Bt[64][68];
  const int t = threadIdx.x;
  #pragma unroll
  for (int l = 0; l < 4; ++l) {
    const int v = t + l * 256;
    const int r = v >> 4, c4 = (v & 15) << 2;
    const float4 pv = *(const float4*)(P + r * 64 + c4);
    Pt[c4 + 0][r] = pv.x; Pt[c4 + 1][r] = pv.y;
    Pt[c4 + 2][r] = pv.z; Pt[c4 + 3][r] = pv.w;
    *(float4*)&Bt[r][c4] = *(const float4*)(A + (size_t)(o + r) * MIND + j0 + c4);
  }
  __syncthreads();
  const int ty = t >> 4, tx = t & 15;
  float acc[4][4] = {};
  for (int s = 0; s < 64; ++s) {
    const float4 a4 = *(const float4*)&Pt[s][ty * 4];
    const float4 b4 = *(const float4*)&Bt[s][tx * 4];
    const float a[4] = {a4.x, a4.y, a4.z, a4.w};
    const float b[4] = {b4.x, b4.y, b4.z, b4.w};
    #pragma unroll
    for (int i = 0; i < 4; ++i)
      #pragma unroll
      for (int j = 0; j < 4; ++j) acc[i][j] += a[i] * b[j];
  }
  #pragma unroll
  for (int i = 0; i < 4; ++i) {
    float4 o4; o4.x = acc[i][0]; o4.y = acc[i][1]; o4.z = acc[i][2]; o4.w = acc[i][3];
    *(float4*)(A + (size_t)(o + ty * 4 + i) * MIND + j0 + tx * 4) = o4;
  }
}

__global__ __launch_bounds__(256) void gj_big(float* __restrict__ A, int o)
{
  const int j0 = blockIdx.x * 64, i0 = blockIdx.y * 64;
  if (i0 == o || j0 == o) return;
  __shared__ float Ct[64][68];
  __shared__ float Rw[64][68];
  const int t = threadIdx.x;
  #pragma unroll
  for (int l = 0; l < 4; ++l) {
    const int v = t + l * 256;
    const int r = v >> 4, c4 = (v & 15) << 2;
    const float4 av = *(const float4*)(A + (size_t)(i0 + r) * MIND + o + c4);
    Ct[c4 + 0][r] = av.x; Ct[c4 + 1][r] = av.y;
    Ct[c4 + 2][r] = av.z; Ct[c4 + 3][r] = av.w;
    *(float4*)&Rw[r][c4] = *(const float4*)(A + (size_t)(o + r) * MIND + j0 + c4);
  }
  __syncthreads();
  const int ty = t >> 4, tx = t & 15;
  float acc[4][4] = {};
  for (int k = 0; k < 64; ++k) {
    const float4 a4 = *(const float4*)&Ct[k][ty * 4];
    const float4 b4 = *(const float4*)&Rw[k][tx * 4];
    const float a[4] = {a4.x, a4.y, a4.z, a4.w};
    const float b[4] = {b4.x, b4.y, b4.z, b4.w};
    #pragma unroll
    for (int i = 0; i < 4; ++i)
      #pragma unroll
      for (int j = 0; j < 4; ++j) acc[i][j] += a[i] * b[j];
  }
  #pragma unroll
  for (int i = 0; i < 4; ++i) {
    float* cp = A + (size_t)(i0 + ty * 4 + i) * MIND + j0 + tx * 4;
    float4 cv = *(const float4*)cp;
    cv.x -= acc[i][0]; cv.y -= acc[i][1]; cv.z -= acc[i][2]; cv.w -= acc[i][3];
    *(float4*)cp = cv;
  }
}

__global__ __launch_bounds__(256) void gj_col(
    float* __restrict__ A, const float* __restrict__ P, int o)
{
  const int i0 = blockIdx.x * 64;
  if (i0 == o) return;
  __shared__ float Ot[64][68];
  __shared__ float Pl[64][68];
  const int t = threadIdx.x;
  #pragma unroll
  for (int l = 0; l < 4; ++l) {
    const int v = t + l * 256;
    const int r = v >> 4, c4 = (v & 15) << 2;
    const float4 av = *(const float4*)(A + (size_t)(i0 + r) * MIND + o + c4);
    Ot[c4 + 0][r] = av.x; Ot[c4 + 1][r] = av.y;
    Ot[c4 + 2][r] = av.z; Ot[c4 + 3][r] = av.w;
    *(float4*)&Pl[r][c4] = *(const float4*)(P + r * 64 + c4);
  }
  __syncthreads();
  const int ty = t >> 4, tx = t & 15;
  float acc[4][4] = {};
  for (int s = 0; s < 64; ++s) {
    const float4 a4 = *(const float4*)&Ot[s][ty * 4];
    const float4 b4 = *(const float4*)&Pl[s][tx * 4];
    const float a[4] = {a4.x, a4.y, a4.z, a4.w};
    const float b[4] = {b4.x, b4.y, b4.z, b4.w};
    #pragma unroll
    for (int i = 0; i < 4; ++i)
      #pragma unroll
      for (int j = 0; j < 4; ++j) acc[i][j] += a[i] * b[j];
  }
  #pragma unroll
  for (int i = 0; i < 4; ++i) {
    float4 o4;
    o4.x = -acc[i][0]; o4.y = -acc[i][1]; o4.z = -acc[i][2]; o4.w = -acc[i][3];
    *(float4*)(A + (size_t)(i0 + ty * 4 + i) * MIND + o + tx * 4) = o4;
  }
}

// ----------------------------------------------------------- helpers -------
// u = rowsum(Kinv)  (Kinv symmetric: rowsum == colsum)
__global__ __launch_bounds__(256) void rowsum_kernel(
    const float* __restrict__ Ai, float* __restrict__ u)
{
  const int row = blockIdx.x * 4 + (threadIdx.x >> 6);
  const int lane = threadIdx.x & 63;
  float s = 0.f;
  for (int c = lane; c < MIND; c += 64) s += Ai[(size_t)row * MIND + c];
  #pragma unroll
  for (int off = 32; off; off >>= 1) s += __shfl_xor(s, off);
  if (lane == 0) u[row] = s;
}

typedef _Float16 half4v __attribute__((ext_vector_type(4)));
__global__ __launch_bounds__(256) void cast_half4(
    const float* __restrict__ s, _Float16* __restrict__ d)
{
  const int i = (blockIdx.x * 256 + threadIdx.x) * 4;
  const float4 v = *(const float4*)(s + i);
  half4v h; h.x = (_Float16)v.x; h.y = (_Float16)v.y;
  h.z = (_Float16)v.z; h.w = (_Float16)v.w;
  *(half4v*)(d + i) = h;
}

// Rt[512,2048] = fp16(R[2048,512]^T)
__global__ __launch_bounds__(256) void transpose_cast(
    const float* __restrict__ R, _Float16* __restrict__ Rt)
{
  __shared__ float T[64][65];
  const int j0 = blockIdx.x * 64;   // R rows
  const int f0 = blockIdx.y * 64;   // R cols
  const int t = threadIdx.x;
  #pragma unroll
  for (int l = 0; l < 16; ++l) {
    const int idx = t + l * 256;
    T[idx >> 6][idx & 63] = R[(size_t)(j0 + (idx >> 6)) * NF + f0 + (idx & 63)];
  }
  __syncthreads();
  #pragma unroll
  for (int l = 0; l < 16; ++l) {
    const int idx = t + l * 256;
    const int fr = idx >> 6, jc = idx & 63;
    Rt[(size_t)(f0 + fr) * MIND + j0 + jc] = (_Float16)T[jc][fr];
  }
}

__global__ __launch_bounds__(256) void colsum_kernel(
    const float* __restrict__ R, float* __restrict__ cs)
{
  const int b = blockIdx.x;   // 32 blocks x 64 rows
  const int t = threadIdx.x;
  float s0 = 0.f, s1 = 0.f;
  for (int r = 0; r < 64; ++r) {
    s0 += R[(size_t)(b * 64 + r) * NF + t];
    s1 += R[(size_t)(b * 64 + r) * NF + t + 256];
  }
  atomicAdd(&cs[t], s0); atomicAdd(&cs[t + 256], s1);
}

__global__ __launch_bounds__(256) void var_finalize(
    const float* __restrict__ varacc, const int* __restrict__ mask,
    float* __restrict__ outv)
{
  const int i = blockIdx.x * 256 + threadIdx.x;
  const float m = (mask[i] != 0) ? 1.f : 0.f;
  outv[i] = (1.0f - varacc[i]) * m;
}

}  // namespace

extern "C" void kernel_launch(void* const* d_in, const int* in_sizes, int n_in,
                              void* d_out, int out_size, void* d_ws, size_t ws_size,
                              hipStream_t stream)
{
  (void)in_sizes; (void)n_in; (void)out_size; (void)ws_size;
  const float* x     = (const float*)d_in[0];
  const int*   mask  = (const int*)d_in[1];
  const float* ip    = (const float*)d_in[2];
  const float* gamma = (const float*)d_in[3];
  float* out = (float*)d_out;

  float* w       = (float*)d_ws;
  float* sum     = w;                         // 512
  float* sumsq   = w + 512;                   // 512
  float* cnt     = w + 1024;                  // 1 (padded 512)
  float* varacc  = w + 1536;                  // 16384
  float* colsumR = w + 17920;                 // 512
  //   [0 .. 18432) zeroed each call
  float* meanv   = w + 18432;
  float* stdv    = w + 18944;
  float* zsv     = w + 19456;
  float* giv     = w + 19968;
  float* rnorm   = w + 20480;                 // 16384
  float* cnorm   = w + 36864;                 // 2048
  float* u       = w + 38912;                 // 2048
  float* Ai      = w + 40960;                 // 2048*2048 (Kreg -> Kinv)
  float* Pd      = w + 40960 + 4194304 - 4096;// reuse tail? no: separate below
  float* R       = w + 4235264;               // 2048*512
  float* Pdiag   = w + 5283840;               // 64*64 GJ scratch
  _Float16* hb   = (_Float16*)(w + 5283840 + 4096);
  _Float16* Zh   = hb;                        // 16384*512
  _Float16* Zih  = hb + 8388608;              // 2048*512
  _Float16* DK   = hb + 9437184;              // 16384*2048
  _Float16* Kih  = hb + 42991616;             // 2048*2048
  _Float16* Rt   = hb + 47185920;             // 512*2048
  (void)Pd;

  hipMemsetAsync(w, 0, 18432 * sizeof(float), stream);

  stats_kernel<<<256, 256, 0, stream>>>(x, mask, sum, sumsq, cnt);
  finalize_stats<<<2, 256, 0, stream>>>(sum, sumsq, cnt, gamma, meanv, stdv, zsv, giv);
  make_z<<<NROW + MIND, 256, 0, stream>>>(x, mask, ip, meanv, zsv, giv, Zh, Zih, rnorm, cnorm);

  // DK = fp16(exp(-|rn+cn-2 Z Zi^T|) - CC)     [16384 x 2048]
  mfma_gemm<0><<<dim3(MIND / 128, NROW / 128), 256, 0, stream>>>(
      Zh, Zih, NROW, MIND, NF, rnorm, cnorm,
      DK, nullptr, nullptr, nullptr, nullptr, nullptr, nullptr, nullptr, nullptr);
  // Kreg fp32 = exp(-|...|) + 0.05 I           [2048 x 2048]
  mfma_gemm<1><<<dim3(MIND / 128, MIND / 128), 256, 0, stream>>>(
      Zih, Zih, MIND, MIND, NF, cnorm, cnorm,
      nullptr, Ai, nullptr, nullptr, nullptr, nullptr, nullptr, nullptr, nullptr);

  // in-place blocked Gauss-Jordan inverse (SPD, no pivoting)
  for (int o = 0; o < MIND; o += 64) {
    gj_diag<<<1, 256, 0, stream>>>(Ai, Pdiag, o);
    gj_row<<<32, 256, 0, stream>>>(Ai, Pdiag, o);
    gj_big<<<dim3(32, 32), 256, 0, stream>>>(Ai, o);
    gj_col<<<32, 256, 0, stream>>>(Ai, Pdiag, o);
  }

  // R = Kinv * P (fp32), then Rt = fp16(R^T), colsumR, u = rowsum(Kinv), Kih
  gemm_f32<<<dim3(NF / 64, MIND / 64), 256, 0, stream>>>(Ai, ip, R, MIND, NF, MIND);
  transpose_cast<<<dim3(MIND / 64, NF / 64), 256, 0, stream>>>(R, Rt);
  colsum_kernel<<<MIND / 64, 256, 0, stream>>>(R, colsumR);
  rowsum_kernel<<<MIND / 4, 256, 0, stream>>>(Ai, u);
  cast_half4<<<(MIND * MIND) / 1024, 256, 0, stream>>>(Ai, Kih);

  // varacc_i = sum_j (DK Kinv + CC*1 u^T)_ij * (CC + DK_ij)
  mfma_gemm<2><<<dim3(MIND / 128, NROW / 128), 256, 0, stream>>>(
      DK, Kih, NROW, MIND, MIND, nullptr, nullptr,
      nullptr, nullptr, DK, u, varacc, nullptr, nullptr, nullptr, nullptr);

  // x_new = ((DK Rt^T + CC*colsumR)*std + mean) * mask
  mfma_gemm<3><<<dim3(NF / 128, NROW / 128), 256, 0, stream>>>(
      DK, Rt, NROW, NF, MIND, nullptr, nullptr,
      nullptr, out, nullptr, nullptr, nullptr, colsumR, stdv, meanv, mask);

  var_finalize<<<NROW / 256, 256, 0, stream>>>(varacc, mask, out + (size_t)NROW * NF);
}

// Round 3
// 2169.818 us; speedup vs baseline: 2.0718x; 1.1245x over previous
//
#include <hip/hip_runtime.h>
#include <math.h>
#include <stdint.h>

namespace {

constexpr int NROW = 16384;   // B*A
constexpr int NF   = 512;     // n_in
constexpr int MIND = 2048;    // inducing points
constexpr float CC = 0.98f;   // centering constant: Kx = exp(-d), d ~ 0.004

typedef _Float16 half8 __attribute__((ext_vector_type(8)));
typedef float floatx4 __attribute__((ext_vector_type(4)));

__device__ __forceinline__ void gload16(const void* g, void* l) {
  __builtin_amdgcn_global_load_lds(
      (__attribute__((address_space(1))) void*)g,
      (__attribute__((address_space(3))) void*)l, 16, 0, 0);
}

// ---------------------------------------------------------------- stats ----
__global__ __launch_bounds__(256) void stats_kernel(
    const float* __restrict__ x, const int* __restrict__ mask,
    float* __restrict__ sum, float* __restrict__ sumsq, float* __restrict__ cnt)
{
  const int t = threadIdx.x;
  const int row0 = blockIdx.x * 64;
  float s0 = 0.f, s1 = 0.f, q0 = 0.f, q1 = 0.f, c = 0.f;
  for (int r = 0; r < 64; ++r) {
    const int row = row0 + r;
    const float m = (mask[row] != 0) ? 1.f : 0.f;
    const float v0 = x[(size_t)row * NF + t];
    const float v1 = x[(size_t)row * NF + t + 256];
    s0 += m * v0; q0 += m * v0 * v0;
    s1 += m * v1; q1 += m * v1 * v1;
    c += m;
  }
  atomicAdd(&sum[t], s0);        atomicAdd(&sum[t + 256], s1);
  atomicAdd(&sumsq[t], q0);      atomicAdd(&sumsq[t + 256], q1);
  if (t == 0) atomicAdd(cnt, c);
}

__global__ __launch_bounds__(256) void finalize_stats(
    const float* __restrict__ sum, const float* __restrict__ sumsq,
    const float* __restrict__ cnt, const float* __restrict__ gamma,
    float* __restrict__ meanv, float* __restrict__ stdv,
    float* __restrict__ zsv, float* __restrict__ giv)
{
  const int f = blockIdx.x * 256 + threadIdx.x;   // <<<2,256>>>
  const float n = cnt[0];
  const float mu = sum[f] / n;
  const float var = (sumsq[f] - sum[f] * mu) / (n - 1.0f);
  const float sd = sqrtf(var) + 1e-5f;
  const float g = gamma[f];
  const float g2 = g * g + 0.001f;
  meanv[f] = mu;
  stdv[f]  = sd;
  zsv[f]   = 1.0f / (sd * g2);
  giv[f]   = 1.0f / g2;
}

// z rows (masked, normalized, /g2) fp16 + zi rows fp16 + fp32 norms of the
// fp16-ROUNDED values (so d_jj ~ 0 exactly)
__global__ __launch_bounds__(256) void make_z(
    const float* __restrict__ x, const int* __restrict__ mask,
    const float* __restrict__ ip, const float* __restrict__ meanv,
    const float* __restrict__ zsv, const float* __restrict__ giv,
    _Float16* __restrict__ Zh, _Float16* __restrict__ Zih,
    float* __restrict__ rnorm, float* __restrict__ cnorm)
{
  const int row = blockIdx.x;
  const int t = threadIdx.x;
  float v0, v1;
  if (row < NROW) {
    const float m = (mask[row] != 0) ? 1.f : 0.f;
    v0 = (x[(size_t)row * NF + t      ] - meanv[t      ]) * zsv[t      ] * m;
    v1 = (x[(size_t)row * NF + t + 256] - meanv[t + 256]) * zsv[t + 256] * m;
    const _Float16 h0 = (_Float16)v0, h1 = (_Float16)v1;
    Zh[(size_t)row * NF + t] = h0;
    Zh[(size_t)row * NF + t + 256] = h1;
    v0 = (float)h0; v1 = (float)h1;
  } else {
    const int r = row - NROW;
    v0 = ip[(size_t)r * NF + t      ] * giv[t      ];
    v1 = ip[(size_t)r * NF + t + 256] * giv[t + 256];
    const _Float16 h0 = (_Float16)v0, h1 = (_Float16)v1;
    Zih[(size_t)r * NF + t] = h0;
    Zih[(size_t)r * NF + t + 256] = h1;
    v0 = (float)h0; v1 = (float)h1;
  }
  float nrm = v0 * v0 + v1 * v1;
  #pragma unroll
  for (int off = 32; off; off >>= 1) nrm += __shfl_xor(nrm, off);
  __shared__ float red[4];
  if ((t & 63) == 0) red[t >> 6] = nrm;
  __syncthreads();
  if (t == 0) {
    const float s = red[0] + red[1] + red[2] + red[3];
    if (row < NROW) rnorm[row] = s; else cnorm[row - NROW] = s;
  }
}

// ---------------------------------------------------------- MFMA GEMM ------
// S[M,N] = A[M,K] * B[N,K]^T, fp16 K-contiguous, fp32 accumulate.
// EPI 0: DKout = fp16(exp(-|rn_i + cn_j - 2S|) - CC)                [Kx gen]
// EPI 1: Cf = exp(-|rn_i + cn_j - 2S|) + 0.05*(i==j)  fp32          [Kreg]
// EPI 2: varacc_i += sum_j (S_ij + CC*u_j) * (CC + DK_ij)           [t o Kx]
// EPI 3: Cf = ((S_ij + CC*colsumR_j)*stdv_j + meanv_j) * mask_i     [x_new]
template <int EPI>
__global__ __launch_bounds__(256) void mfma_gemm(
    const _Float16* __restrict__ A, const _Float16* __restrict__ B,
    int M, int N, int K,
    const float* __restrict__ rn, const float* __restrict__ cn,
    _Float16* __restrict__ DKout, float* __restrict__ Cf,
    const _Float16* __restrict__ DK, const float* __restrict__ u,
    float* __restrict__ varacc,
    const float* __restrict__ colsumR,
    const float* __restrict__ stdv, const float* __restrict__ meanv,
    const int* __restrict__ mask)
{
  __shared__ __align__(16) _Float16 As[128 * 32];
  __shared__ __align__(16) _Float16 Bs[128 * 32];
  const int tid = threadIdx.x;
  const int w = tid >> 6, L = tid & 63;
  const int wm = w >> 1, wn = w & 1;
  const int bn = blockIdx.x, bm = blockIdx.y;
  const int lq = L >> 4;
  const int lr = L & 15;

  floatx4 acc[4][4] = {};

  const _Float16* Ag = A + (size_t)(bm * 128) * K;
  const _Float16* Bg = B + (size_t)(bn * 128) * K;
  const int srow = w * 32 + (L >> 2);
  const int scol = (L & 3) * 8;

  for (int k0 = 0; k0 < K; k0 += 32) {
    #pragma unroll
    for (int t = 0; t < 2; ++t) {
      const int r = srow + t * 16;
      gload16(Ag + (size_t)r * K + k0 + scol, As + r * 32 + scol);
      gload16(Bg + (size_t)r * K + k0 + scol, Bs + r * 32 + scol);
    }
    __syncthreads();
    half8 af[4], bf[4];
    #pragma unroll
    for (int mi = 0; mi < 4; ++mi)
      af[mi] = *(const half8*)&As[(wm * 64 + mi * 16 + lr) * 32 + lq * 8];
    #pragma unroll
    for (int ni = 0; ni < 4; ++ni)
      bf[ni] = *(const half8*)&Bs[(wn * 64 + ni * 16 + lr) * 32 + lq * 8];
    #pragma unroll
    for (int mi = 0; mi < 4; ++mi)
      #pragma unroll
      for (int ni = 0; ni < 4; ++ni)
        acc[mi][ni] = __builtin_amdgcn_mfma_f32_16x16x32_f16(
            af[mi], bf[ni], acc[mi][ni], 0, 0, 0);
    __syncthreads();
  }

  // C/D layout: col = lane&15, row = (lane>>4)*4 + reg
  const int grb = bm * 128 + wm * 64;
  const int gcb = bn * 128 + wn * 64;

  if constexpr (EPI == 2) {
    #pragma unroll
    for (int mi = 0; mi < 4; ++mi)
      #pragma unroll
      for (int e = 0; e < 4; ++e) {
        const int gr = grb + mi * 16 + lq * 4 + e;
        float partial = 0.f;
        #pragma unroll
        for (int ni = 0; ni < 4; ++ni) {
          const int gc = gcb + ni * 16 + lr;
          const float t = acc[mi][ni][e] + CC * u[gc];
          const float kx = CC + (float)DK[(size_t)gr * N + gc];
          partial += t * kx;
        }
        partial += __shfl_xor(partial, 1);
        partial += __shfl_xor(partial, 2);
        partial += __shfl_xor(partial, 4);
        partial += __shfl_xor(partial, 8);
        if (lr == 0) atomicAdd(&varacc[gr], partial);
      }
  } else if constexpr (EPI == 3) {
    #pragma unroll
    for (int mi = 0; mi < 4; ++mi)
      #pragma unroll
      for (int e = 0; e < 4; ++e) {
        const int gr = grb + mi * 16 + lq * 4 + e;
        const float mrow = (mask[gr] != 0) ? 1.f : 0.f;
        #pragma unroll
        for (int ni = 0; ni < 4; ++ni) {
          const int gc = gcb + ni * 16 + lr;
          const float v = acc[mi][ni][e] + CC * colsumR[gc];
          Cf[(size_t)gr * N + gc] = (v * stdv[gc] + meanv[gc]) * mrow;
        }
      }
  } else {
    #pragma unroll
    for (int mi = 0; mi < 4; ++mi)
      #pragma unroll
      for (int e = 0; e < 4; ++e) {
        const int gr = grb + mi * 16 + lq * 4 + e;
        const float rni = rn[gr];
        #pragma unroll
        for (int ni = 0; ni < 4; ++ni) {
          const int gc = gcb + ni * 16 + lr;
          const float d = rni + cn[gc] - 2.f * acc[mi][ni][e];
          float kx = expf(-fabsf(d));
          if constexpr (EPI == 0) {
            DKout[(size_t)gr * N + gc] = (_Float16)(kx - CC);
          } else {
            if (gr == gc) kx += 0.05f;
            Cf[(size_t)gr * N + gc] = kx;
          }
        }
      }
  }
}

// ------------------------------------------------------------ fp32 GEMM ----
// C[M,N] = A[M,K]*B[K,N], 64x64 tile (R = Kinv * P only; ~20 us)
__global__ __launch_bounds__(256) void gemm_f32(
    const float* __restrict__ A, const float* __restrict__ B,
    float* __restrict__ C, int M, int N, int K)
{
  constexpr int BM = 64, BN = 64, BK = 16;
  const int tid = threadIdx.x;
  const int tx = tid % 16, ty = tid / 16;
  const int bn = blockIdx.x, bm = blockIdx.y;
  __shared__ float As[BK][BM + 4];
  __shared__ float Bs[BK][BN + 4];
  float acc[4][4] = {};
  const float* Ag = A + (size_t)bm * BM * K;
  const float* Bg = B + bn * BN;
  for (int k0 = 0; k0 < K; k0 += BK) {
    {
      const int r = tid >> 2, c4 = (tid & 3) << 2;
      const float4 av = *(const float4*)(Ag + (size_t)r * K + k0 + c4);
      As[c4 + 0][r] = av.x; As[c4 + 1][r] = av.y;
      As[c4 + 2][r] = av.z; As[c4 + 3][r] = av.w;
      const int kr = tid / 16, nc = (tid % 16) << 2;
      *(float4*)&Bs[kr][nc] = *(const float4*)(Bg + (size_t)(k0 + kr) * N + nc);
    }
    __syncthreads();
    #pragma unroll
    for (int kk = 0; kk < BK; ++kk) {
      const float4 a4 = *(const float4*)&As[kk][ty * 4];
      const float4 b4 = *(const float4*)&Bs[kk][tx * 4];
      const float a[4] = {a4.x, a4.y, a4.z, a4.w};
      const float b[4] = {b4.x, b4.y, b4.z, b4.w};
      #pragma unroll
      for (int i = 0; i < 4; ++i)
        #pragma unroll
        for (int j = 0; j < 4; ++j) acc[i][j] += a[i] * b[j];
    }
    __syncthreads();
  }
  #pragma unroll
  for (int i = 0; i < 4; ++i) {
    float4 o4; o4.x = acc[i][0]; o4.y = acc[i][1]; o4.z = acc[i][2]; o4.w = acc[i][3];
    *(float4*)(C + (size_t)(bm * BM + ty * 4 + i) * N + bn * BN + tx * 4) = o4;
  }
}

// ------------------------------------------------- blocked Gauss-Jordan ----
// Restructured: 2 launches/iter.  Per iter k (o = 64k):
//   gj_apply: row A_oj = P*Bsave_j; col A_io = -CP_i; big A_ij -= CP_i*Bsave_j;
//             block (o+64,o+64) also runs the 64-step pivot loop -> Pall[k+1]
//   gj_prep:  CP_i = A[i][o']*P';  Bsave = copy of row panel A[o'][:]
// Bootstrap: gj_diag computes Pall[0] from A_00.

__global__ __launch_bounds__(256) void gj_diag(
    float* __restrict__ A, float* __restrict__ Pall, int k)
{
  const int o = k * 64;
  __shared__ float D[64][68];
  const int t = threadIdx.x;
  #pragma unroll
  for (int l = 0; l < 4; ++l) {
    const int v = t + l * 256;
    const int r = v >> 4, c4 = (v & 15) << 2;
    *(float4*)&D[r][c4] = *(const float4*)(A + (size_t)(o + r) * MIND + o + c4);
  }
  __syncthreads();
  const int i = t >> 2, c0 = (t & 3) * 16;
  for (int s = 0; s < 64; ++s) {
    const float p = 1.0f / D[s][s];
    if (t < 64 && t != s) D[s][t] *= p;
    __syncthreads();
    if (i != s) {
      const float f = D[i][s];
      #pragma unroll
      for (int c = c0; c < c0 + 16; c += 4) {
        float4 ds = *(const float4*)&D[s][c];
        float4 di = *(const float4*)&D[i][c];
        di.x -= f * ds.x; di.y -= f * ds.y; di.z -= f * ds.z; di.w -= f * ds.w;
        *(float4*)&D[i][c] = di;
      }
      if (s >= c0 && s < c0 + 16) D[i][s] = -f * p;
    }
    if (t == 0) D[s][s] = p;
    __syncthreads();
  }
  float* P = Pall + k * 4096;
  #pragma unroll
  for (int l = 0; l < 4; ++l) {
    const int v = t + l * 256;
    const int r = v >> 4, c4 = (v & 15) << 2;
    const float4 dv = *(const float4*)&D[r][c4];
    *(float4*)(P + r * 64 + c4) = dv;
    *(float4*)(A + (size_t)(o + r) * MIND + o + c4) = dv;
  }
}

// 64 blocks: bx<32 -> CP_i = A[i][o]*P (skip i==o); bx>=32 -> Bsave row copy
__global__ __launch_bounds__(256) void gj_prep(
    const float* __restrict__ A, const float* __restrict__ Pall,
    float* __restrict__ CP, float* __restrict__ Bsave, int k)
{
  const int o = k * 64;
  const int t = threadIdx.x;
  if (blockIdx.x >= 32) {
    const int j0 = (blockIdx.x - 32) * 64;
    #pragma unroll
    for (int l = 0; l < 4; ++l) {
      const int v = t + l * 256;
      const int r = v >> 4, c4 = (v & 15) << 2;
      *(float4*)(Bsave + r * MIND + j0 + c4) =
          *(const float4*)(A + (size_t)(o + r) * MIND + j0 + c4);
    }
    return;
  }
  const int i0 = blockIdx.x * 64;
  if (i0 == o) return;
  const float* P = Pall + k * 4096;
  __shared__ float At[64][68];   // At[s][r] = A[i0+r][o+s]
  __shared__ float Pl[64][68];   // Pl[s][c] = P[s][c]
  #pragma unroll
  for (int l = 0; l < 4; ++l) {
    const int v = t + l * 256;
    const int r = v >> 4, c4 = (v & 15) << 2;
    const float4 av = *(const float4*)(A + (size_t)(i0 + r) * MIND + o + c4);
    At[c4 + 0][r] = av.x; At[c4 + 1][r] = av.y;
    At[c4 + 2][r] = av.z; At[c4 + 3][r] = av.w;
    *(float4*)&Pl[r][c4] = *(const float4*)(P + r * 64 + c4);
  }
  __syncthreads();
  const int ty = t >> 4, tx = t & 15;
  float acc[4][4] = {};
  for (int s = 0; s < 64; ++s) {
    const float4 a4 = *(const float4*)&At[s][ty * 4];
    const float4 b4 = *(const float4*)&Pl[s][tx * 4];
    const float a[4] = {a4.x, a4.y, a4.z, a4.w};
    const float b[4] = {b4.x, b4.y, b4.z, b4.w};
    #pragma unroll
    for (int i = 0; i < 4; ++i)
      #pragma unroll
      for (int j = 0; j < 4; ++j) acc[i][j] += a[i] * b[j];
  }
  #pragma unroll
  for (int i = 0; i < 4; ++i) {
    float4 o4; o4.x = acc[i][0]; o4.y = acc[i][1]; o4.z = acc[i][2]; o4.w = acc[i][3];
    *(float4*)(CP + (i0 + ty * 4 + i) * 64 + tx * 4) = o4;
  }
}

__global__ __launch_bounds__(256) void gj_apply(
    float* __restrict__ A, float* __restrict__ Pall,
    const float* __restrict__ CP, const float* __restrict__ Bsave, int k)
{
  const int o = k * 64;
  const int i0 = blockIdx.y * 64, j0 = blockIdx.x * 64;
  const int t = threadIdx.x;

  if (i0 == o && j0 == o) return;

  if (j0 == o) {                       // col: A_io = -CP_i (negated copy)
    #pragma unroll
    for (int l = 0; l < 4; ++l) {
      const int v = t + l * 256;
      const int r = v >> 4, c4 = (v & 15) << 2;
      float4 x = *(const float4*)(CP + (i0 + r) * 64 + c4);
      x.x = -x.x; x.y = -x.y; x.z = -x.z; x.w = -x.w;
      *(float4*)(A + (size_t)(i0 + r) * MIND + o + c4) = x;
    }
    return;
  }

  __shared__ float S1[64 * 68];   // Lt (transposed left op); later D for diag
  __shared__ float S2[64 * 68];   // Bsave tile
  #define DD(r, c) S1[(r) * 68 + (c)]

  const bool isrow = (i0 == o);
  const float* Lsrc = isrow ? (Pall + k * 4096) : (CP + i0 * 64);
  #pragma unroll
  for (int l = 0; l < 4; ++l) {
    const int v = t + l * 256;
    const int r = v >> 4, c4 = (v & 15) << 2;
    const float4 lv = *(const float4*)(Lsrc + r * 64 + c4);
    S1[(c4 + 0) * 68 + r] = lv.x; S1[(c4 + 1) * 68 + r] = lv.y;
    S1[(c4 + 2) * 68 + r] = lv.z; S1[(c4 + 3) * 68 + r] = lv.w;
    *(float4*)&S2[r * 68 + c4] = *(const float4*)(Bsave + r * MIND + j0 + c4);
  }
  __syncthreads();
  const int ty = t >> 4, tx = t & 15;
  float acc[4][4] = {};
  for (int s = 0; s < 64; ++s) {
    const float4 a4 = *(const float4*)&S1[s * 68 + ty * 4];
    const float4 b4 = *(const float4*)&S2[s * 68 + tx * 4];
    const float a[4] = {a4.x, a4.y, a4.z, a4.w};
    const float b[4] = {b4.x, b4.y, b4.z, b4.w};
    #pragma unroll
    for (int i = 0; i < 4; ++i)
      #pragma unroll
      for (int j = 0; j < 4; ++j) acc[i][j] += a[i] * b[j];
  }

  if (isrow) {                         // A_oj = P * Bsave_j
    #pragma unroll
    for (int i = 0; i < 4; ++i) {
      float4 o4; o4.x = acc[i][0]; o4.y = acc[i][1]; o4.z = acc[i][2]; o4.w = acc[i][3];
      *(float4*)(A + (size_t)(o + ty * 4 + i) * MIND + j0 + tx * 4) = o4;
    }
    return;
  }

  const bool isdiagnext = (i0 == o + 64) && (j0 == o + 64);
  if (!isdiagnext) {                   // big: A_ij -= CP_i * Bsave_j
    #pragma unroll
    for (int i = 0; i < 4; ++i) {
      float* cp = A + (size_t)(i0 + ty * 4 + i) * MIND + j0 + tx * 4;
      float4 cv = *(const float4*)cp;
      cv.x -= acc[i][0]; cv.y -= acc[i][1]; cv.z -= acc[i][2]; cv.w -= acc[i][3];
      *(float4*)cp = cv;
    }
    return;
  }

  // diag-next: update into LDS, run 64-step pivot loop, emit Pall[k+1] + A
  __syncthreads();                     // S1 readers done
  #pragma unroll
  for (int i = 0; i < 4; ++i) {
    const float4 cv = *(const float4*)(A + (size_t)(i0 + ty * 4 + i) * MIND + j0 + tx * 4);
    DD(ty * 4 + i, tx * 4 + 0) = cv.x - acc[i][0];
    DD(ty * 4 + i, tx * 4 + 1) = cv.y - acc[i][1];
    DD(ty * 4 + i, tx * 4 + 2) = cv.z - acc[i][2];
    DD(ty * 4 + i, tx * 4 + 3) = cv.w - acc[i][3];
  }
  __syncthreads();
  const int di = t >> 2, c0 = (t & 3) * 16;
  for (int s = 0; s < 64; ++s) {
    const float p = 1.0f / DD(s, s);
    if (t < 64 && t != s) DD(s, t) *= p;
    __syncthreads();
    if (di != s) {
      const float f = DD(di, s);
      #pragma unroll
      for (int c = c0; c < c0 + 16; c += 4) {
        float4 ds = *(const float4*)&DD(s, c);
        float4 dv = *(const float4*)&DD(di, c);
        dv.x -= f * ds.x; dv.y -= f * ds.y; dv.z -= f * ds.z; dv.w -= f * ds.w;
        *(float4*)&DD(di, c) = dv;
      }
      if (s >= c0 && s < c0 + 16) DD(di, s) = -f * p;
    }
    if (t == 0) DD(s, s) = p;
    __syncthreads();
  }
  float* Pn = Pall + (k + 1) * 4096;
  #pragma unroll
  for (int l = 0; l < 4; ++l) {
    const int v = t + l * 256;
    const int r = v >> 4, c4 = (v & 15) << 2;
    const float4 dv = *(const float4*)&DD(r, c4);
    *(float4*)(Pn + r * 64 + c4) = dv;
    *(float4*)(A + (size_t)(i0 + r) * MIND + j0 + c4) = dv;
  }
  #undef DD
}

// ----------------------------------------------------------- helpers -------
__global__ __launch_bounds__(256) void rowsum_kernel(
    const float* __restrict__ Ai, float* __restrict__ u)
{
  const int row = blockIdx.x * 4 + (threadIdx.x >> 6);
  const int lane = threadIdx.x & 63;
  float s = 0.f;
  for (int c = lane; c < MIND; c += 64) s += Ai[(size_t)row * MIND + c];
  #pragma unroll
  for (int off = 32; off; off >>= 1) s += __shfl_xor(s, off);
  if (lane == 0) u[row] = s;
}

typedef _Float16 half4v __attribute__((ext_vector_type(4)));
__global__ __launch_bounds__(256) void cast_half4(
    const float* __restrict__ s, _Float16* __restrict__ d)
{
  const int i = (blockIdx.x * 256 + threadIdx.x) * 4;
  const float4 v = *(const float4*)(s + i);
  half4v h; h.x = (_Float16)v.x; h.y = (_Float16)v.y;
  h.z = (_Float16)v.z; h.w = (_Float16)v.w;
  *(half4v*)(d + i) = h;
}

// Rt[512,2048] = fp16(R[2048,512]^T)
__global__ __launch_bounds__(256) void transpose_cast(
    const float* __restrict__ R, _Float16* __restrict__ Rt)
{
  __shared__ float T[64][65];
  const int j0 = blockIdx.x * 64;
  const int f0 = blockIdx.y * 64;
  const int t = threadIdx.x;
  #pragma unroll
  for (int l = 0; l < 16; ++l) {
    const int idx = t + l * 256;
    T[idx >> 6][idx & 63] = R[(size_t)(j0 + (idx >> 6)) * NF + f0 + (idx & 63)];
  }
  __syncthreads();
  #pragma unroll
  for (int l = 0; l < 16; ++l) {
    const int idx = t + l * 256;
    const int fr = idx >> 6, jc = idx & 63;
    Rt[(size_t)(f0 + fr) * MIND + j0 + jc] = (_Float16)T[jc][fr];
  }
}

__global__ __launch_bounds__(256) void colsum_kernel(
    const float* __restrict__ R, float* __restrict__ cs)
{
  const int b = blockIdx.x;
  const int t = threadIdx.x;
  float s0 = 0.f, s1 = 0.f;
  for (int r = 0; r < 64; ++r) {
    s0 += R[(size_t)(b * 64 + r) * NF + t];
    s1 += R[(size_t)(b * 64 + r) * NF + t + 256];
  }
  atomicAdd(&cs[t], s0); atomicAdd(&cs[t + 256], s1);
}

__global__ __launch_bounds__(256) void var_finalize(
    const float* __restrict__ varacc, const int* __restrict__ mask,
    float* __restrict__ outv)
{
  const int i = blockIdx.x * 256 + threadIdx.x;
  const float m = (mask[i] != 0) ? 1.f : 0.f;
  outv[i] = (1.0f - varacc[i]) * m;
}

}  // namespace

extern "C" void kernel_launch(void* const* d_in, const int* in_sizes, int n_in,
                              void* d_out, int out_size, void* d_ws, size_t ws_size,
                              hipStream_t stream)
{
  (void)in_sizes; (void)n_in; (void)out_size; (void)ws_size;
  const float* x     = (const float*)d_in[0];
  const int*   mask  = (const int*)d_in[1];
  const float* ip    = (const float*)d_in[2];
  const float* gamma = (const float*)d_in[3];
  float* out = (float*)d_out;

  float* w       = (float*)d_ws;
  float* sum     = w;                     // 512
  float* sumsq   = w + 512;               // 512
  float* cnt     = w + 1024;              // 1 (padded 512)
  float* varacc  = w + 1536;              // 16384
  float* colsumR = w + 17920;             // 512   -> [0, 18432) zeroed
  float* meanv   = w + 18432;
  float* stdv    = w + 18944;
  float* zsv     = w + 19456;
  float* giv     = w + 19968;
  float* rnorm   = w + 20480;             // 16384
  float* cnorm   = w + 36864;             // 2048
  float* u       = w + 38912;             // 2048
  float* Ai      = w + 40960;             // 2048*2048 (Kreg -> Kinv in place)
  float* R       = w + 4235264;           // 2048*512
  float* Pall    = w + 5283840;           // 32*4096 pivot inverses
  float* CP      = w + 5414912;           // 2048*64
  float* Bsave   = w + 5545984;           // 64*2048
  _Float16* hb   = (_Float16*)(w + 5677056);
  _Float16* Zh   = hb;                    // 16384*512
  _Float16* Zih  = hb + 8388608;          // 2048*512
  _Float16* DK   = hb + 9437184;          // 16384*2048
  _Float16* Kih  = hb + 42991616;         // 2048*2048
  _Float16* Rt   = hb + 47185920;         // 512*2048

  hipMemsetAsync(w, 0, 18432 * sizeof(float), stream);

  stats_kernel<<<256, 256, 0, stream>>>(x, mask, sum, sumsq, cnt);
  finalize_stats<<<2, 256, 0, stream>>>(sum, sumsq, cnt, gamma, meanv, stdv, zsv, giv);
  make_z<<<NROW + MIND, 256, 0, stream>>>(x, mask, ip, meanv, zsv, giv, Zh, Zih, rnorm, cnorm);

  // DK = fp16(exp(-|rn+cn-2 Z Zi^T|) - CC)     [16384 x 2048]
  mfma_gemm<0><<<dim3(MIND / 128, NROW / 128), 256, 0, stream>>>(
      Zh, Zih, NROW, MIND, NF, rnorm, cnorm,
      DK, nullptr, nullptr, nullptr, nullptr, nullptr, nullptr, nullptr, nullptr);
  // Kreg fp32 = exp(-|...|) + 0.05 I           [2048 x 2048]
  mfma_gemm<1><<<dim3(MIND / 128, MIND / 128), 256, 0, stream>>>(
      Zih, Zih, MIND, MIND, NF, cnorm, cnorm,
      nullptr, Ai, nullptr, nullptr, nullptr, nullptr, nullptr, nullptr, nullptr);

  // blocked Gauss-Jordan inverse, 2 launches/iter, diag hidden in apply
  gj_diag<<<1, 256, 0, stream>>>(Ai, Pall, 0);
  gj_prep<<<64, 256, 0, stream>>>(Ai, Pall, CP, Bsave, 0);
  for (int k = 0; k < 32; ++k) {
    gj_apply<<<dim3(32, 32), 256, 0, stream>>>(Ai, Pall, CP, Bsave, k);
    if (k < 31) gj_prep<<<64, 256, 0, stream>>>(Ai, Pall, CP, Bsave, k + 1);
  }

  // R = Kinv * P (fp32), then Rt = fp16(R^T), colsumR, u = rowsum(Kinv), Kih
  gemm_f32<<<dim3(NF / 64, MIND / 64), 256, 0, stream>>>(Ai, ip, R, MIND, NF, MIND);
  transpose_cast<<<dim3(MIND / 64, NF / 64), 256, 0, stream>>>(R, Rt);
  colsum_kernel<<<MIND / 64, 256, 0, stream>>>(R, colsumR);
  rowsum_kernel<<<MIND / 4, 256, 0, stream>>>(Ai, u);
  cast_half4<<<(MIND * MIND) / 1024, 256, 0, stream>>>(Ai, Kih);

  // varacc_i = sum_j (DK Kinv + CC*1 u^T)_ij * (CC + DK_ij)
  mfma_gemm<2><<<dim3(MIND / 128, NROW / 128), 256, 0, stream>>>(
      DK, Kih, NROW, MIND, MIND, nullptr, nullptr,
      nullptr, nullptr, DK, u, varacc, nullptr, nullptr, nullptr, nullptr);

  // x_new = ((DK Rt^T + CC*colsumR)*std + mean) * mask
  mfma_gemm<3><<<dim3(NF / 128, NROW / 128), 256, 0, stream>>>(
      DK, Rt, NROW, NF, MIND, nullptr, nullptr,
      nullptr, out, nullptr, nullptr, nullptr, colsumR, stdv, meanv, mask);

  var_finalize<<<NROW / 256, 256, 0, stream>>>(varacc, mask, out + (size_t)NROW * NF);
}